// Round 3
// baseline (203.259 us; speedup 1.0000x reference)
//
#include <hip/hip_runtime.h>

#define Lc 1024
#define Dc 512
#define Hc 8
#define DHc 64

typedef __attribute__((ext_vector_type(8))) short bf16x8;
typedef __attribute__((ext_vector_type(4))) float f32x4;

typedef __attribute__((address_space(1))) const unsigned int guint;
typedef __attribute__((address_space(3))) unsigned int luint;

__device__ __forceinline__ void gload_lds16(const void* g, void* l) {
    __builtin_amdgcn_global_load_lds((guint*)g, (luint*)l, 16, 0, 0);
}

__device__ __forceinline__ unsigned short f2bf(float f) {
    unsigned u = __float_as_uint(f);
    u += 0x7fffu + ((u >> 16) & 1u);          // round-to-nearest-even
    return (unsigned short)(u >> 16);
}
__device__ __forceinline__ unsigned short f2bft(float f) {   // truncate
    return (unsigned short)(__float_as_uint(f) >> 16);
}
__device__ __forceinline__ unsigned pk2(float a, float b) {
    return (unsigned)f2bf(a) | ((unsigned)f2bf(b) << 16);
}
__device__ __forceinline__ float bf2f(unsigned short s) { return __uint_as_float(((unsigned)s) << 16); }

// ---------------------------------------------------------------------------
// fp32 -> bf16 cast of x, Wq, Wk, Wv, Wo, We
// ---------------------------------------------------------------------------
__global__ void cvt_all_kernel(
    const float* __restrict__ x,  const float* __restrict__ Wq,
    const float* __restrict__ Wk, const float* __restrict__ Wv,
    const float* __restrict__ Wo, const float* __restrict__ We,
    unsigned short* __restrict__ xb,  unsigned short* __restrict__ wqb,
    unsigned short* __restrict__ wkb, unsigned short* __restrict__ wvb,
    unsigned short* __restrict__ wob, unsigned short* __restrict__ wet)
{
    int bid = blockIdx.x;
    const float* src; unsigned short* dst; size_t base;
    if      (bid < 4096) { src = x;  dst = xb;  base = (size_t)bid * 1024; }
    else if (bid < 4352) { src = Wq; dst = wqb; base = (size_t)(bid-4096) * 1024; }
    else if (bid < 4608) { src = Wk; dst = wkb; base = (size_t)(bid-4352) * 1024; }
    else if (bid < 4864) { src = Wv; dst = wvb; base = (size_t)(bid-4608) * 1024; }
    else if (bid < 5120) { src = Wo; dst = wob; base = (size_t)(bid-4864) * 1024; }
    else                 { src = We; dst = wet; base = (size_t)(bid-5120) * 1024; }
    size_t i = base + (size_t)threadIdx.x * 4;
    float4 a = *(const float4*)&src[i];
    *(uint2*)&dst[i] = make_uint2(pk2(a.x, a.y), pk2(a.z, a.w));
}

// ---------------------------------------------------------------------------
// QKV projection, bf16 MFMA, BK=64, full-DMA staging (R6-proven config).
// Normal orientation for all z; q/k epilogue: quad-contiguous scalar stores;
// z==2 (v): LDS-transpose epilogue -> V^T (B,H,DH,L).
// qscale = 0.125*log2(e) folded into Q.
// ---------------------------------------------------------------------------
__global__ __launch_bounds__(256, 3) void proj_mfma_kernel(
    const unsigned short* __restrict__ xb,
    const unsigned short* __restrict__ wq, const unsigned short* __restrict__ wk,
    const unsigned short* __restrict__ wv,
    unsigned short* __restrict__ qo, unsigned short* __restrict__ ko,
    unsigned short* __restrict__ vtg, float qscale)
{
    const unsigned short* W;
    if (blockIdx.z == 0)      W = wq;
    else if (blockIdx.z == 1) W = wk;
    else                      W = wv;

    __shared__ unsigned short smem[128 * 136];      // As(8192) Bs(8192) / Ts(17408)
    unsigned short* As = smem;
    unsigned short* Bs = smem + 8192;

    const int t = threadIdx.x;
    const int lane = t & 63, w = t >> 6;
    const int lq = lane >> 4, ln = lane & 15;
    const int m0 = blockIdx.y * 128, n0 = blockIdx.x * 128;
    const int wm = (w & 1) * 64, wn = (w >> 1) * 64;
    const int srow = t >> 3;                        // 0..31
    const int lsg  = ((t & 7) ^ ((t >> 3) & 7)) * 8;  // swizzled source seg*8
    const int key  = ln & 7;

    f32x4 acc[4][4];
    #pragma unroll
    for (int i = 0; i < 4; i++)
        #pragma unroll
        for (int j = 0; j < 4; j++) acc[i][j] = (f32x4){0.f,0.f,0.f,0.f};

    for (int c0 = 0; c0 < 512; c0 += 64) {
        __syncthreads();
        #pragma unroll
        for (int g = 0; g < 4; g++) {
            gload_lds16(&xb[(size_t)(m0 + 32*g + srow) * 512 + c0 + lsg], &As[(32*g + srow)*64 + (t&7)*8]);
            gload_lds16(&W [(size_t)(n0 + 32*g + srow) * 512 + c0 + lsg], &Bs[(32*g + srow)*64 + (t&7)*8]);
        }
        __syncthreads();

        #pragma unroll
        for (int kk = 0; kk < 2; kk++) {
            bf16x8 af[4], bf[4];
            #pragma unroll
            for (int i = 0; i < 4; i++)
                af[i] = *(bf16x8*)&As[(wm + 16*i + ln)*64 + ((kk*4 + lq) ^ key)*8];
            #pragma unroll
            for (int j = 0; j < 4; j++)
                bf[j] = *(bf16x8*)&Bs[(wn + 16*j + ln)*64 + ((kk*4 + lq) ^ key)*8];
            #pragma unroll
            for (int i = 0; i < 4; i++)
                #pragma unroll
                for (int j = 0; j < 4; j++)
                    acc[i][j] = __builtin_amdgcn_mfma_f32_16x16x32_bf16(af[i], bf[j], acc[i][j], 0, 0, 0);
        }
    }

    if (blockIdx.z < 2) {
        unsigned short* out = (blockIdx.z == 0) ? qo : ko;
        const float osc = (blockIdx.z == 0) ? qscale : 1.0f;
        #pragma unroll
        for (int i = 0; i < 4; i++) {
            #pragma unroll
            for (int r = 0; r < 4; r++) {
                int m = m0 + wm + 16*i + 4*lq + r;
                int b = m >> 10, l = m & 1023;
                #pragma unroll
                for (int j = 0; j < 4; j++) {
                    int n = n0 + wn + 16*j + ln;
                    int h = n >> 6, dh = n & 63;
                    out[((size_t)((b*Hc + h)*Lc + l))*DHc + dh] = f2bf(acc[i][j][r] * osc);
                }
            }
        }
    } else {
        // V: transpose through LDS, write V^T (B,H,DH,L)
        __syncthreads();
        unsigned short* Ts = smem;      // [n_local][m_local] stride 136
        #pragma unroll
        for (int i = 0; i < 4; i++) {
            int mlb = wm + 16*i + 4*lq;
            #pragma unroll
            for (int j = 0; j < 4; j++) {
                int nl = wn + 16*j + ln;
                *(uint2*)&Ts[nl*136 + mlb] = make_uint2(pk2(acc[i][j][0], acc[i][j][1]),
                                                        pk2(acc[i][j][2], acc[i][j][3]));
            }
        }
        __syncthreads();
        const int b = m0 >> 10, l0m = m0 & 1023;
        const int nl = t >> 1, seg = (t & 1) * 64;
        const int ng = n0 + nl, h = ng >> 6, dh = ng & 63;
        unsigned short* dst = vtg + (((size_t)(b*Hc + h))*DHc + dh)*Lc + l0m + seg;
        #pragma unroll
        for (int u = 0; u < 8; u++)
            *(uint4*)&dst[8*u] = *(uint4*)&Ts[nl*136 + seg + 8*u];
    }
}

// ---------------------------------------------------------------------------
// Output GEMM, bf16 MFMA, 64x64 tiles (1024 blocks = 4/CU). BK=64, swizzled
// DMA. out = awb @ Wo^T + bo (fp32 out).
// ---------------------------------------------------------------------------
__global__ __launch_bounds__(256, 4) void out_mfma_kernel(
    const unsigned short* __restrict__ A, const unsigned short* __restrict__ W,
    const float* __restrict__ bias, float* __restrict__ out)
{
    __shared__ unsigned short As[64 * 64];
    __shared__ unsigned short Bs[64 * 64];

    const int t = threadIdx.x;
    const int lane = t & 63, w = t >> 6;
    const int lq = lane >> 4, ln = lane & 15;
    const int m0 = blockIdx.y * 64, n0 = blockIdx.x * 64;
    const int wm = (w & 1) * 32, wn = (w >> 1) * 32;
    const int srow = t >> 3;                        // 0..31
    const int lsg  = ((t & 7) ^ ((t >> 3) & 7)) * 8;
    const int key  = ln & 7;

    f32x4 acc[2][2];
    #pragma unroll
    for (int i = 0; i < 2; i++)
        #pragma unroll
        for (int j = 0; j < 2; j++) acc[i][j] = (f32x4){0.f,0.f,0.f,0.f};

    for (int c0 = 0; c0 < 512; c0 += 64) {
        __syncthreads();
        #pragma unroll
        for (int g = 0; g < 2; g++) {
            gload_lds16(&A[(size_t)(m0 + 32*g + srow) * 512 + c0 + lsg], &As[(32*g + srow)*64 + (t&7)*8]);
            gload_lds16(&W[(size_t)(n0 + 32*g + srow) * 512 + c0 + lsg], &Bs[(32*g + srow)*64 + (t&7)*8]);
        }
        __syncthreads();

        #pragma unroll
        for (int kk = 0; kk < 2; kk++) {
            bf16x8 af[2], bf[2];
            #pragma unroll
            for (int i = 0; i < 2; i++)
                af[i] = *(bf16x8*)&As[(wm + 16*i + ln)*64 + ((kk*4 + lq) ^ key)*8];
            #pragma unroll
            for (int j = 0; j < 2; j++)
                bf[j] = *(bf16x8*)&Bs[(wn + 16*j + ln)*64 + ((kk*4 + lq) ^ key)*8];
            #pragma unroll
            for (int i = 0; i < 2; i++)
                #pragma unroll
                for (int j = 0; j < 2; j++)
                    acc[i][j] = __builtin_amdgcn_mfma_f32_16x16x32_bf16(af[i], bf[j], acc[i][j], 0, 0, 0);
        }
    }

    float bb[2];
    #pragma unroll
    for (int j = 0; j < 2; j++) bb[j] = bias[n0 + wn + 16*j + ln];

    #pragma unroll
    for (int i = 0; i < 2; i++) {
        #pragma unroll
        for (int r = 0; r < 4; r++) {
            int m = m0 + wm + 16*i + 4*lq + r;
            #pragma unroll
            for (int j = 0; j < 2; j++) {
                int n = n0 + wn + 16*j + ln;
                out[(size_t)m * Dc + n] = acc[i][j][r] + bb[j];
            }
        }
    }
}

// ---------------------------------------------------------------------------
// attn v8: K / V^T / We fragments loaded REGISTER-DIRECT from global (L2-
// resident per the bh XCD swizzle) instead of LDS staging. The old staging
// swizzle and the reader swizzle cancel exactly, so the reg-direct address is
// the plain 16B-contiguous global row chunk. Eliminates all global_load_lds
// DMA + 12 of 16 b128 LDS reads per wave-iter; QK becomes fully register-
// resident; barriers 4 -> 2 per iter. LDS keeps only qes ring (16 KB) and
// the P exchange buffer ps (8 KB).
// ---------------------------------------------------------------------------
__global__ __launch_bounds__(256, 4) void attn_v8_kernel(
    const unsigned short* __restrict__ q, const unsigned short* __restrict__ k,
    const unsigned short* __restrict__ vtg, const unsigned short* __restrict__ wet,
    unsigned short* __restrict__ attn)
{
    __shared__ unsigned short ps  [2 * 64 * 32];    // 8192  P planes [wc][lr][32]
    __shared__ unsigned short qes [128 * 64];       // 16384 QE ring [slot][col^swz]
    // total 24576 B

    const int t    = threadIdx.x;
    const int lane = t & 63, w = t >> 6;
    const int lq   = lane >> 4, ln = lane & 15;
    const int wr   = (w >> 1) * 32;                 // row-base within block: 0/32
    const int wc   = w & 1;                         // col-half: 0/1

    const int n   = blockIdx.x;
    const int xcd = n & 7, idx = n >> 3;
    const int bh  = xcd * 8 + (idx >> 4);
    const int l0  = (idx & 15) * 64;

    const unsigned short* qb  = q   + (size_t)bh * (Lc * DHc);
    const unsigned short* kb  = k   + (size_t)bh * (Lc * DHc);
    const unsigned short* vtb = vtg + (size_t)bh * (DHc * Lc);

    const int swz  = (ln >> 2) & 3;                 // for ps b128 reads only

    const bf16x8 onesf = {(short)0x3F80,(short)0x3F80,(short)0x3F80,(short)0x3F80,
                          (short)0x3F80,(short)0x3F80,(short)0x3F80,(short)0x3F80};

    // Q rows for this wave: wr + 16*rg + ln (rg = 0,1)
    bf16x8 qa[2][2];
    #pragma unroll
    for (int rg = 0; rg < 2; rg++)
        #pragma unroll
        for (int kk = 0; kk < 2; kk++)
            qa[rg][kk] = *(const bf16x8*)&qb[(size_t)(l0 + wr + 16*rg + ln)*64 + kk*32 + lq*8];

    // pre-loop QE panel pb0, We read register-direct
    const int pb0 = 15 - (l0 >> 6);
    {
        f32x4 qec[2][2];
        #pragma unroll
        for (int rg = 0; rg < 2; rg++)
            #pragma unroll
            for (int ct = 0; ct < 2; ct++) qec[rg][ct] = (f32x4){0.f,0.f,0.f,0.f};
        #pragma unroll
        for (int kk = 0; kk < 2; kk++)
            #pragma unroll
            for (int ct = 0; ct < 2; ct++) {
                bf16x8 bf = *(const bf16x8*)&wet[(size_t)(64*pb0 + 16*(2*wc+ct) + ln)*64 + kk*32 + lq*8];
                #pragma unroll
                for (int rg = 0; rg < 2; rg++)
                    qec[rg][ct] = __builtin_amdgcn_mfma_f32_16x16x32_bf16(qa[rg][kk], bf, qec[rg][ct], 0, 0, 0);
            }
        const int cb = (pb0 & 1) * 64;
        #pragma unroll
        for (int ct = 0; ct < 2; ct++) {
            const int row = cb + 16*(2*wc+ct) + ln;               // (row&15)==ln
            #pragma unroll
            for (int rg = 0; rg < 2; rg++)
                *(uint2*)&qes[row*64 + ((wr + 16*rg + 4*lq) ^ (ln << 2))] =
                    make_uint2(pk2(qec[rg][ct][0], qec[rg][ct][1]),
                               pk2(qec[rg][ct][2], qec[rg][ct][3]));
        }
    }

    f32x4 Lacc[2];
    f32x4 Ov[2][2];
    #pragma unroll
    for (int rg = 0; rg < 2; rg++) {
        Lacc[rg] = (f32x4){0.f,0.f,0.f,0.f};
        #pragma unroll
        for (int ct = 0; ct < 2; ct++) Ov[rg][ct] = (f32x4){0.f,0.f,0.f,0.f};
    }

    int pbOld = pb0 - 1;

    for (int s0 = 0; s0 < Lc; s0 += 64) {
        const int c0  = l0 - s0;
        const int ac0 = c0 < 0 ? -c0 : c0;
        const int pb  = (960 - ac0) >> 6;
        const int newp = (pb > pbOld) ? pb + 1 : pb;
        pbOld = pb;
        const int cb = (newp & 1) * 64;

        // ---- register-direct fragment loads (issue early) ----
        bf16x8 wfr[2][2], kfr[2][2];
        #pragma unroll
        for (int kk = 0; kk < 2; kk++)
            #pragma unroll
            for (int ct = 0; ct < 2; ct++) {
                const int row = 16*(2*wc+ct) + ln;
                wfr[kk][ct] = *(const bf16x8*)&wet[(size_t)(64*newp + row)*64 + kk*32 + lq*8];
                kfr[kk][ct] = *(const bf16x8*)&kb [(size_t)(s0 + row)*64 + kk*32 + lq*8];
            }

        // ---- QE: new panel ----
        {
            f32x4 qec[2][2];
            #pragma unroll
            for (int rg = 0; rg < 2; rg++)
                #pragma unroll
                for (int ct = 0; ct < 2; ct++) qec[rg][ct] = (f32x4){0.f,0.f,0.f,0.f};
            #pragma unroll
            for (int kk = 0; kk < 2; kk++)
                #pragma unroll
                for (int ct = 0; ct < 2; ct++)
                    #pragma unroll
                    for (int rg = 0; rg < 2; rg++)
                        qec[rg][ct] = __builtin_amdgcn_mfma_f32_16x16x32_bf16(qa[rg][kk], wfr[kk][ct], qec[rg][ct], 0, 0, 0);
            #pragma unroll
            for (int ct = 0; ct < 2; ct++) {
                const int row = cb + 16*(2*wc+ct) + ln;           // (row&15)==ln
                #pragma unroll
                for (int rg = 0; rg < 2; rg++)
                    *(uint2*)&qes[row*64 + ((wr + 16*rg + 4*lq) ^ (ln << 2))] =
                        make_uint2(pk2(qec[rg][ct][0], qec[rg][ct][1]),
                                   pk2(qec[rg][ct][2], qec[rg][ct][3]));
            }
        }

        // bar1: qes panel visible for bias reads; prev-iter PV ps-reads done
        // before this iter's P-writes
        __syncthreads();

        // ---- V^T fragments (used after bar2; load early to hide latency) ----
        bf16x8 vfr[2][2];
        #pragma unroll
        for (int kk = 0; kk < 2; kk++)
            #pragma unroll
            for (int ct = 0; ct < 2; ct++)
                vfr[kk][ct] = *(const bf16x8*)&vtb[(size_t)(16*(2*wc+ct) + ln)*1024 + s0 + kk*32 + lq*8];

        // ---- QK^T: fully register-resident ----
        f32x4 sc[2][2];
        #pragma unroll
        for (int rg = 0; rg < 2; rg++)
            #pragma unroll
            for (int ct = 0; ct < 2; ct++) sc[rg][ct] = (f32x4){0.f,0.f,0.f,0.f};
        #pragma unroll
        for (int kk = 0; kk < 2; kk++)
            #pragma unroll
            for (int ct = 0; ct < 2; ct++)
                #pragma unroll
                for (int rg = 0; rg < 2; rg++)
                    sc[rg][ct] = __builtin_amdgcn_mfma_f32_16x16x32_bf16(qa[rg][kk], kfr[kk][ct], sc[rg][ct], 0, 0, 0);

        // ---- bias + exp2 + P write ----
        #pragma unroll
        for (int rg = 0; rg < 2; rg++)
            #pragma unroll
            for (int r = 0; r < 4; r++) {
                const int lr = wr + 16*rg + 4*lq + r;
                const int dbase = c0 + lr - ln;
                #pragma unroll
                for (int ct = 0; ct < 2; ct++) {
                    int d  = dbase - 16*(2*wc+ct);
                    int ad = d < 0 ? -d : d;
                    int m  = 1023 - ad;
                    float bias = bf2f(qes[(m & 127)*64 + (lr ^ ((m & 15) << 2))]);
                    float pv = __builtin_amdgcn_exp2f(sc[rg][ct][r] + bias);
                    int seg = ((ct*2 + (ln >> 3)) ^ lq);
                    ps[wc*2048 + lr*32 + seg*8 + (ln & 7)] = f2bft(pv);
                }
            }

        // bar2: P visible for cross-wave PV; bias reads done before next-iter
        // QE panel overwrites ring slots
        __syncthreads();

        // ---- PV: this wave's 32 rows x 32 dh-cols, contract all 64 s ----
        #pragma unroll
        for (int kk = 0; kk < 2; kk++) {
            bf16x8 pa[2];
            #pragma unroll
            for (int rg = 0; rg < 2; rg++)
                pa[rg] = *(bf16x8*)&ps[kk*2048 + (wr + 16*rg + ln)*32 + (lq ^ swz)*8];
            #pragma unroll
            for (int rg = 0; rg < 2; rg++)
                Lacc[rg] = __builtin_amdgcn_mfma_f32_16x16x32_bf16(pa[rg], onesf, Lacc[rg], 0, 0, 0);
            #pragma unroll
            for (int ct = 0; ct < 2; ct++)
                #pragma unroll
                for (int rg = 0; rg < 2; rg++)
                    Ov[rg][ct] = __builtin_amdgcn_mfma_f32_16x16x32_bf16(pa[rg], vfr[kk][ct], Ov[rg][ct], 0, 0, 0);
        }
    }

    const int b = bh >> 3, h = bh & 7;
    #pragma unroll
    for (int rg = 0; rg < 2; rg++)
        #pragma unroll
        for (int r = 0; r < 4; r++) {
            float inv = 1.f / Lacc[rg][r];
            int l = l0 + wr + 16*rg + 4*lq + r;
            #pragma unroll
            for (int ct = 0; ct < 2; ct++)
                attn[((size_t)(b*Lc + l))*Dc + h*DHc + 16*(2*wc+ct) + ln] = f2bf(Ov[rg][ct][r] * inv);
        }
}

extern "C" void kernel_launch(void* const* d_in, const int* in_sizes, int n_in,
                              void* d_out, int out_size, void* d_ws, size_t ws_size,
                              hipStream_t stream)
{
    (void)in_sizes; (void)n_in; (void)out_size; (void)ws_size;
    const float* x  = (const float*)d_in[0];
    const float* Wq = (const float*)d_in[1];
    const float* Wk = (const float*)d_in[2];
    const float* Wv = (const float*)d_in[3];
    const float* We = (const float*)d_in[4];
    const float* Wo = (const float*)d_in[5];
    const float* bo = (const float*)d_in[6];

    const size_t NT = (size_t)8 * Hc * Lc * DHc;     // 4,194,304 elems
    unsigned short* qw  = (unsigned short*)d_ws;
    unsigned short* kw  = qw  + NT;
    unsigned short* vtg = kw  + NT;                  // V^T (B,H,DH,L)
    unsigned short* xbf = vtg + NT;
    unsigned short* awb = xbf + NT;                  // attn out bf16 (B,L,D)
    unsigned short* wqb = awb + NT;
    unsigned short* wkb = wqb + 262144;
    unsigned short* wvb = wkb + 262144;
    unsigned short* wob = wvb + 262144;
    unsigned short* wet = wob + 262144;              // 65536 + 4096 pad (panel-16 overread)

    cvt_all_kernel<<<5184, 256, 0, stream>>>(x, Wq, Wk, Wv, Wo, We,
                                             xbf, wqb, wkb, wvb, wob, wet);
    proj_mfma_kernel<<<dim3(4, 64, 3), 256, 0, stream>>>(xbf, wqb, wkb, wvb,
                                                         qw, kw, vtg,
                                                         0.125f * 1.44269504089f);
    attn_v8_kernel<<<1024, 256, 0, stream>>>(qw, kw, vtg, wet, awb);
    out_mfma_kernel<<<dim3(8, 128), 256, 0, stream>>>(awb, wob, bo, (float*)d_out);
}

// Round 4
// 170.578 us; speedup vs baseline: 1.1916x; 1.1916x over previous
//
#include <hip/hip_runtime.h>

#define Lc 1024
#define Dc 512
#define Hc 8
#define DHc 64

typedef __attribute__((ext_vector_type(8))) short bf16x8;
typedef __attribute__((ext_vector_type(4))) float f32x4;

typedef __attribute__((address_space(1))) const unsigned int guint;
typedef __attribute__((address_space(3))) unsigned int luint;

__device__ __forceinline__ void gload_lds16(const void* g, void* l) {
    __builtin_amdgcn_global_load_lds((guint*)g, (luint*)l, 16, 0, 0);
}

__device__ __forceinline__ unsigned short f2bf(float f) {
    unsigned u = __float_as_uint(f);
    u += 0x7fffu + ((u >> 16) & 1u);          // round-to-nearest-even
    return (unsigned short)(u >> 16);
}
__device__ __forceinline__ unsigned pk2(float a, float b) {
    return (unsigned)f2bf(a) | ((unsigned)f2bf(b) << 16);
}
__device__ __forceinline__ unsigned pk2t(float a, float b) {   // truncating pack, 1 v_perm
    return __builtin_amdgcn_perm(__float_as_uint(b), __float_as_uint(a), 0x07060302u);
}
__device__ __forceinline__ float bf2f(unsigned short s) { return __uint_as_float(((unsigned)s) << 16); }

// ---------------------------------------------------------------------------
// fp32 -> bf16 cast of x, Wq, Wk, Wv, Wo, We
// ---------------------------------------------------------------------------
__global__ void cvt_all_kernel(
    const float* __restrict__ x,  const float* __restrict__ Wq,
    const float* __restrict__ Wk, const float* __restrict__ Wv,
    const float* __restrict__ Wo, const float* __restrict__ We,
    unsigned short* __restrict__ xb,  unsigned short* __restrict__ wqb,
    unsigned short* __restrict__ wkb, unsigned short* __restrict__ wvb,
    unsigned short* __restrict__ wob, unsigned short* __restrict__ wet)
{
    int bid = blockIdx.x;
    const float* src; unsigned short* dst; size_t base;
    if      (bid < 4096) { src = x;  dst = xb;  base = (size_t)bid * 1024; }
    else if (bid < 4352) { src = Wq; dst = wqb; base = (size_t)(bid-4096) * 1024; }
    else if (bid < 4608) { src = Wk; dst = wkb; base = (size_t)(bid-4352) * 1024; }
    else if (bid < 4864) { src = Wv; dst = wvb; base = (size_t)(bid-4608) * 1024; }
    else if (bid < 5120) { src = Wo; dst = wob; base = (size_t)(bid-4864) * 1024; }
    else                 { src = We; dst = wet; base = (size_t)(bid-5120) * 1024; }
    size_t i = base + (size_t)threadIdx.x * 4;
    float4 a = *(const float4*)&src[i];
    *(uint2*)&dst[i] = make_uint2(pk2(a.x, a.y), pk2(a.z, a.w));
}

// ---------------------------------------------------------------------------
// QKV projection, bf16 MFMA, BK=64, full-DMA staging (R6-proven config).
// ---------------------------------------------------------------------------
__global__ __launch_bounds__(256, 3) void proj_mfma_kernel(
    const unsigned short* __restrict__ xb,
    const unsigned short* __restrict__ wq, const unsigned short* __restrict__ wk,
    const unsigned short* __restrict__ wv,
    unsigned short* __restrict__ qo, unsigned short* __restrict__ ko,
    unsigned short* __restrict__ vtg, float qscale)
{
    const unsigned short* W;
    if (blockIdx.z == 0)      W = wq;
    else if (blockIdx.z == 1) W = wk;
    else                      W = wv;

    __shared__ unsigned short smem[128 * 136];      // As(8192) Bs(8192) / Ts(17408)
    unsigned short* As = smem;
    unsigned short* Bs = smem + 8192;

    const int t = threadIdx.x;
    const int lane = t & 63, w = t >> 6;
    const int lq = lane >> 4, ln = lane & 15;
    const int m0 = blockIdx.y * 128, n0 = blockIdx.x * 128;
    const int wm = (w & 1) * 64, wn = (w >> 1) * 64;
    const int srow = t >> 3;                        // 0..31
    const int lsg  = ((t & 7) ^ ((t >> 3) & 7)) * 8;  // swizzled source seg*8
    const int key  = ln & 7;

    f32x4 acc[4][4];
    #pragma unroll
    for (int i = 0; i < 4; i++)
        #pragma unroll
        for (int j = 0; j < 4; j++) acc[i][j] = (f32x4){0.f,0.f,0.f,0.f};

    for (int c0 = 0; c0 < 512; c0 += 64) {
        __syncthreads();
        #pragma unroll
        for (int g = 0; g < 4; g++) {
            gload_lds16(&xb[(size_t)(m0 + 32*g + srow) * 512 + c0 + lsg], &As[(32*g + srow)*64 + (t&7)*8]);
            gload_lds16(&W [(size_t)(n0 + 32*g + srow) * 512 + c0 + lsg], &Bs[(32*g + srow)*64 + (t&7)*8]);
        }
        __syncthreads();

        #pragma unroll
        for (int kk = 0; kk < 2; kk++) {
            bf16x8 af[4], bf[4];
            #pragma unroll
            for (int i = 0; i < 4; i++)
                af[i] = *(bf16x8*)&As[(wm + 16*i + ln)*64 + ((kk*4 + lq) ^ key)*8];
            #pragma unroll
            for (int j = 0; j < 4; j++)
                bf[j] = *(bf16x8*)&Bs[(wn + 16*j + ln)*64 + ((kk*4 + lq) ^ key)*8];
            #pragma unroll
            for (int i = 0; i < 4; i++)
                #pragma unroll
                for (int j = 0; j < 4; j++)
                    acc[i][j] = __builtin_amdgcn_mfma_f32_16x16x32_bf16(af[i], bf[j], acc[i][j], 0, 0, 0);
        }
    }

    if (blockIdx.z < 2) {
        unsigned short* out = (blockIdx.z == 0) ? qo : ko;
        const float osc = (blockIdx.z == 0) ? qscale : 1.0f;
        #pragma unroll
        for (int i = 0; i < 4; i++) {
            #pragma unroll
            for (int r = 0; r < 4; r++) {
                int m = m0 + wm + 16*i + 4*lq + r;
                int b = m >> 10, l = m & 1023;
                #pragma unroll
                for (int j = 0; j < 4; j++) {
                    int n = n0 + wn + 16*j + ln;
                    int h = n >> 6, dh = n & 63;
                    out[((size_t)((b*Hc + h)*Lc + l))*DHc + dh] = f2bf(acc[i][j][r] * osc);
                }
            }
        }
    } else {
        // V: transpose through LDS, write V^T (B,H,DH,L)
        __syncthreads();
        unsigned short* Ts = smem;      // [n_local][m_local] stride 136
        #pragma unroll
        for (int i = 0; i < 4; i++) {
            int mlb = wm + 16*i + 4*lq;
            #pragma unroll
            for (int j = 0; j < 4; j++) {
                int nl = wn + 16*j + ln;
                *(uint2*)&Ts[nl*136 + mlb] = make_uint2(pk2(acc[i][j][0], acc[i][j][1]),
                                                        pk2(acc[i][j][2], acc[i][j][3]));
            }
        }
        __syncthreads();
        const int b = m0 >> 10, l0m = m0 & 1023;
        const int nl = t >> 1, seg = (t & 1) * 64;
        const int ng = n0 + nl, h = ng >> 6, dh = ng & 63;
        unsigned short* dst = vtg + (((size_t)(b*Hc + h))*DHc + dh)*Lc + l0m + seg;
        #pragma unroll
        for (int u = 0; u < 8; u++)
            *(uint4*)&dst[8*u] = *(uint4*)&Ts[nl*136 + seg + 8*u];
    }
}

// ---------------------------------------------------------------------------
// Output GEMM, bf16 MFMA, 64x64 tiles (1024 blocks = 4/CU). BK=64, swizzled
// DMA. out = awb @ Wo^T + bo (fp32 out).
// ---------------------------------------------------------------------------
__global__ __launch_bounds__(256, 4) void out_mfma_kernel(
    const unsigned short* __restrict__ A, const unsigned short* __restrict__ W,
    const float* __restrict__ bias, float* __restrict__ out)
{
    __shared__ unsigned short As[64 * 64];
    __shared__ unsigned short Bs[64 * 64];

    const int t = threadIdx.x;
    const int lane = t & 63, w = t >> 6;
    const int lq = lane >> 4, ln = lane & 15;
    const int m0 = blockIdx.y * 64, n0 = blockIdx.x * 64;
    const int wm = (w & 1) * 32, wn = (w >> 1) * 32;
    const int srow = t >> 3;                        // 0..31
    const int lsg  = ((t & 7) ^ ((t >> 3) & 7)) * 8;
    const int key  = ln & 7;

    f32x4 acc[2][2];
    #pragma unroll
    for (int i = 0; i < 2; i++)
        #pragma unroll
        for (int j = 0; j < 2; j++) acc[i][j] = (f32x4){0.f,0.f,0.f,0.f};

    for (int c0 = 0; c0 < 512; c0 += 64) {
        __syncthreads();
        #pragma unroll
        for (int g = 0; g < 2; g++) {
            gload_lds16(&A[(size_t)(m0 + 32*g + srow) * 512 + c0 + lsg], &As[(32*g + srow)*64 + (t&7)*8]);
            gload_lds16(&W[(size_t)(n0 + 32*g + srow) * 512 + c0 + lsg], &Bs[(32*g + srow)*64 + (t&7)*8]);
        }
        __syncthreads();

        #pragma unroll
        for (int kk = 0; kk < 2; kk++) {
            bf16x8 af[2], bf[2];
            #pragma unroll
            for (int i = 0; i < 2; i++)
                af[i] = *(bf16x8*)&As[(wm + 16*i + ln)*64 + ((kk*4 + lq) ^ key)*8];
            #pragma unroll
            for (int j = 0; j < 2; j++)
                bf[j] = *(bf16x8*)&Bs[(wn + 16*j + ln)*64 + ((kk*4 + lq) ^ key)*8];
            #pragma unroll
            for (int i = 0; i < 2; i++)
                #pragma unroll
                for (int j = 0; j < 2; j++)
                    acc[i][j] = __builtin_amdgcn_mfma_f32_16x16x32_bf16(af[i], bf[j], acc[i][j], 0, 0, 0);
        }
    }

    float bb[2];
    #pragma unroll
    for (int j = 0; j < 2; j++) bb[j] = bias[n0 + wn + 16*j + ln];

    #pragma unroll
    for (int i = 0; i < 2; i++) {
        #pragma unroll
        for (int r = 0; r < 4; r++) {
            int m = m0 + wm + 16*i + 4*lq + r;
            #pragma unroll
            for (int j = 0; j < 2; j++) {
                int n = n0 + wn + 16*j + ln;
                out[(size_t)m * Dc + n] = acc[i][j][r] + bb[j];
            }
        }
    }
}

// ---------------------------------------------------------------------------
// attn v9: v7 dataflow (DMA staging, 4-barrier skeleton, qes ring, LDS
// 40960 B) but with TRANSPOSED MFMA orientation:
//   S^T = mfma(K, Q)  -> lane holds col l (ln), rows s = 4lq+r (consecutive!)
//   O^T = mfma(V^T, P^T)
// so each lane's 4 P values are s-contiguous -> ps writes: 16 scalar -> 4
// uint2 (packed via 1 v_perm each pair); epilogue: 16 scalar global stores ->
// 4 uint2. Wave grid: si = s/dh half (w>>1), li = l half (w&1).
// ps2 layout [l][s] with 8-short-block XOR swizzle blk^(row&7).
// ---------------------------------------------------------------------------
__global__ __launch_bounds__(256, 4) void attn_v9_kernel(
    const unsigned short* __restrict__ q, const unsigned short* __restrict__ k,
    const unsigned short* __restrict__ vtg, const unsigned short* __restrict__ wet,
    unsigned short* __restrict__ attn)
{
    __shared__ unsigned short ksp [2 * 64 * 32];    // 8192  K planes [kk][s][32]
    __shared__ unsigned short vtp [2 * 64 * 32];    // 8192  V^T planes [kk][dh][32]
    __shared__ unsigned short ps2 [64 * 64];        // 8192  P^T exchange [l][s-swz]; ALSO We staging alias
    __shared__ unsigned short qes [128 * 64];       // 16384 QE ring [slot][col^swz]
    // total 40960 B -> 4 blocks/CU

    unsigned short* wesp = ps2;                     // alias: We panel staged into ps2

    const int t    = threadIdx.x;
    const int lane = t & 63, w = t >> 6;
    const int lq   = lane >> 4, ln = lane & 15;
    const int si   = w >> 1;                        // s / dh half: 0/1
    const int li   = w & 1;                         // l half: 0/1

    const int n   = blockIdx.x;
    const int xcd = n & 7, idx = n >> 3;
    const int bh  = xcd * 8 + (idx >> 4);
    const int l0  = (idx & 15) * 64;

    const unsigned short* qb  = q   + (size_t)bh * (Lc * DHc);
    const unsigned short* kb  = k   + (size_t)bh * (Lc * DHc);
    const unsigned short* vtb = vtg + (size_t)bh * (DHc * Lc);

    const int trow = t >> 2;
    const int sseg = ((t & 3) ^ ((t >> 4) & 3)) * 8;
    const int swz  = (ln >> 2) & 3;

    const bf16x8 onesf = {(short)0x3F80,(short)0x3F80,(short)0x3F80,(short)0x3F80,
                          (short)0x3F80,(short)0x3F80,(short)0x3F80,(short)0x3F80};

    // Q fragments: lane ln <-> l = l0 + 32*li + 16*lt + ln; lq <-> dh chunk.
    // (identical per-lane layout serves both operand slots of the MFMA)
    bf16x8 qf[2][2];
    #pragma unroll
    for (int lt = 0; lt < 2; lt++)
        #pragma unroll
        for (int kk = 0; kk < 2; kk++)
            qf[lt][kk] = *(const bf16x8*)&qb[(size_t)(l0 + 32*li + 16*lt + ln)*64 + kk*32 + lq*8];

    const int pb0 = 15 - (l0 >> 6);
    gload_lds16(&wet[(size_t)(64*pb0 + trow)*64 +      sseg], &wesp[t*8]);
    gload_lds16(&wet[(size_t)(64*pb0 + trow)*64 + 32 + sseg], &wesp[2048 + t*8]);
    __syncthreads();
    {
        f32x4 qec[2][2];                            // [lt][et]
        #pragma unroll
        for (int lt = 0; lt < 2; lt++)
            #pragma unroll
            for (int et = 0; et < 2; et++) qec[lt][et] = (f32x4){0.f,0.f,0.f,0.f};
        #pragma unroll
        for (int kk = 0; kk < 2; kk++)
            #pragma unroll
            for (int et = 0; et < 2; et++) {
                bf16x8 wf = *(bf16x8*)&wesp[kk*2048 + (16*(2*si+et) + ln)*32 + (lq ^ swz)*8];
                #pragma unroll
                for (int lt = 0; lt < 2; lt++)
                    qec[lt][et] = __builtin_amdgcn_mfma_f32_16x16x32_bf16(qf[lt][kk], wf, qec[lt][et], 0, 0, 0);
            }
        const int cb = (pb0 & 1) * 64;
        #pragma unroll
        for (int et = 0; et < 2; et++) {
            const int row = cb + 16*(2*si+et) + ln;               // (row&15) == e&15
            #pragma unroll
            for (int lt = 0; lt < 2; lt++)
                *(uint2*)&qes[row*64 + ((32*li + 16*lt + 4*lq) ^ (ln << 2))] =
                    make_uint2(pk2(qec[lt][et][0], qec[lt][et][1]),
                               pk2(qec[lt][et][2], qec[lt][et][3]));
        }
    }

    f32x4 Lacc[2];
    f32x4 Ov[2][2];                                 // [dt][lt]
    #pragma unroll
    for (int lt = 0; lt < 2; lt++) {
        Lacc[lt] = (f32x4){0.f,0.f,0.f,0.f};
        #pragma unroll
        for (int dt = 0; dt < 2; dt++) Ov[dt][lt] = (f32x4){0.f,0.f,0.f,0.f};
    }

    int pbOld = pb0 - 1;

    for (int s0 = 0; s0 < Lc; s0 += 64) {
        const int c0  = l0 - s0;
        const int ac0 = c0 < 0 ? -c0 : c0;
        const int pb  = (960 - ac0) >> 6;
        const int newp = (pb > pbOld) ? pb + 1 : pb;
        pbOld = pb;
        const int cb = (newp & 1) * 64;

        __syncthreads();                            // prev PV ps2/vtp reads done
        gload_lds16(&kb [(size_t)(s0 + trow)*64 +      sseg], &ksp [t*8]);
        gload_lds16(&kb [(size_t)(s0 + trow)*64 + 32 + sseg], &ksp [2048 + t*8]);
        gload_lds16(&vtb[(size_t)trow*1024 + s0 +      sseg], &vtp [t*8]);
        gload_lds16(&vtb[(size_t)trow*1024 + s0 + 32 + sseg], &vtp [2048 + t*8]);
        gload_lds16(&wet[(size_t)(64*newp + trow)*64 +      sseg], &wesp[t*8]);
        gload_lds16(&wet[(size_t)(64*newp + trow)*64 + 32 + sseg], &wesp[2048 + t*8]);
        __syncthreads();

        // ---- QE: new panel -> ring ----
        {
            f32x4 qec[2][2];
            #pragma unroll
            for (int lt = 0; lt < 2; lt++)
                #pragma unroll
                for (int et = 0; et < 2; et++) qec[lt][et] = (f32x4){0.f,0.f,0.f,0.f};
            #pragma unroll
            for (int kk = 0; kk < 2; kk++)
                #pragma unroll
                for (int et = 0; et < 2; et++) {
                    bf16x8 wf = *(bf16x8*)&wesp[kk*2048 + (16*(2*si+et) + ln)*32 + (lq ^ swz)*8];
                    #pragma unroll
                    for (int lt = 0; lt < 2; lt++)
                        qec[lt][et] = __builtin_amdgcn_mfma_f32_16x16x32_bf16(qf[lt][kk], wf, qec[lt][et], 0, 0, 0);
                }
            #pragma unroll
            for (int et = 0; et < 2; et++) {
                const int row = cb + 16*(2*si+et) + ln;
                #pragma unroll
                for (int lt = 0; lt < 2; lt++)
                    *(uint2*)&qes[row*64 + ((32*li + 16*lt + 4*lq) ^ (ln << 2))] =
                        make_uint2(pk2(qec[lt][et][0], qec[lt][et][1]),
                                   pk2(qec[lt][et][2], qec[lt][et][3]));
            }
        }

        // ring visible for bias reads; wesp (ps2 alias) reads done before
        // this iter's P writes
        __syncthreads();

        // ---- S^T = mfma(K, Q): rows s = 32si+16st+4lq+r, cols l = 32li+16lt+ln
        f32x4 sc[2][2];                             // [st][lt]
        #pragma unroll
        for (int st = 0; st < 2; st++)
            #pragma unroll
            for (int lt = 0; lt < 2; lt++) sc[st][lt] = (f32x4){0.f,0.f,0.f,0.f};
        #pragma unroll
        for (int kk = 0; kk < 2; kk++)
            #pragma unroll
            for (int st = 0; st < 2; st++) {
                bf16x8 kf = *(bf16x8*)&ksp[kk*2048 + (32*si + 16*st + ln)*32 + (lq ^ swz)*8];
                #pragma unroll
                for (int lt = 0; lt < 2; lt++)
                    sc[st][lt] = __builtin_amdgcn_mfma_f32_16x16x32_bf16(kf, qf[lt][kk], sc[st][lt], 0, 0, 0);
            }

        // ---- bias + exp2 + packed P^T write ----
        #pragma unroll
        for (int st = 0; st < 2; st++)
            #pragma unroll
            for (int lt = 0; lt < 2; lt++) {
                const int lloc = 32*li + 16*lt + ln;
                const int sb   = 32*si + 16*st + 4*lq;
                float p[4];
                #pragma unroll
                for (int r = 0; r < 4; r++) {
                    int d  = c0 + lloc - (sb + r);
                    int ad = d < 0 ? -d : d;
                    int m  = 1023 - ad;
                    float bias = bf2f(qes[(m & 127)*64 + (lloc ^ ((m & 15) << 2))]);
                    p[r] = __builtin_amdgcn_exp2f(sc[st][lt][r] + bias);
                }
                const int blk = (4*si + 2*st + (lq >> 1)) ^ (ln & 7);   // lloc&7 == ln&7
                *(uint2*)&ps2[lloc*64 + blk*8 + (lq & 1)*4] =
                    make_uint2(pk2t(p[0], p[1]), pk2t(p[2], p[3]));
            }

        // P complete before cross-wave PV reads
        __syncthreads();

        // ---- O^T = mfma(V^T, P^T): rows dh = 32si+16dt+4lq+r, cols l ----
        #pragma unroll
        for (int kk = 0; kk < 2; kk++) {
            bf16x8 pf[2];
            #pragma unroll
            for (int lt = 0; lt < 2; lt++) {
                const int row = 32*li + 16*lt + ln;
                pf[lt] = *(bf16x8*)&ps2[row*64 + ((4*kk + lq) ^ (ln & 7))*8];
            }
            #pragma unroll
            for (int lt = 0; lt < 2; lt++)
                Lacc[lt] = __builtin_amdgcn_mfma_f32_16x16x32_bf16(onesf, pf[lt], Lacc[lt], 0, 0, 0);
            #pragma unroll
            for (int dt = 0; dt < 2; dt++) {
                bf16x8 vf = *(bf16x8*)&vtp[kk*2048 + (32*si + 16*dt + ln)*32 + (lq ^ swz)*8];
                #pragma unroll
                for (int lt = 0; lt < 2; lt++)
                    Ov[dt][lt] = __builtin_amdgcn_mfma_f32_16x16x32_bf16(vf, pf[lt], Ov[dt][lt], 0, 0, 0);
            }
        }
    }

    const int b = bh >> 3, h = bh & 7;
    #pragma unroll
    for (int lt = 0; lt < 2; lt++) {
        const float inv = 1.f / Lacc[lt][0];        // all 4 rows identical
        const int l = l0 + 32*li + 16*lt + ln;
        unsigned short* dst = &attn[((size_t)(b*Lc + l))*Dc + h*DHc];
        #pragma unroll
        for (int dt = 0; dt < 2; dt++) {
            const int dh = 32*si + 16*dt + 4*lq;
            *(uint2*)&dst[dh] = make_uint2(pk2(Ov[dt][lt][0]*inv, Ov[dt][lt][1]*inv),
                                           pk2(Ov[dt][lt][2]*inv, Ov[dt][lt][3]*inv));
        }
    }
}

extern "C" void kernel_launch(void* const* d_in, const int* in_sizes, int n_in,
                              void* d_out, int out_size, void* d_ws, size_t ws_size,
                              hipStream_t stream)
{
    (void)in_sizes; (void)n_in; (void)out_size; (void)ws_size;
    const float* x  = (const float*)d_in[0];
    const float* Wq = (const float*)d_in[1];
    const float* Wk = (const float*)d_in[2];
    const float* Wv = (const float*)d_in[3];
    const float* We = (const float*)d_in[4];
    const float* Wo = (const float*)d_in[5];
    const float* bo = (const float*)d_in[6];

    const size_t NT = (size_t)8 * Hc * Lc * DHc;     // 4,194,304 elems
    unsigned short* qw  = (unsigned short*)d_ws;
    unsigned short* kw  = qw  + NT;
    unsigned short* vtg = kw  + NT;                  // V^T (B,H,DH,L)
    unsigned short* xbf = vtg + NT;
    unsigned short* awb = xbf + NT;                  // attn out bf16 (B,L,D)
    unsigned short* wqb = awb + NT;
    unsigned short* wkb = wqb + 262144;
    unsigned short* wvb = wkb + 262144;
    unsigned short* wob = wvb + 262144;
    unsigned short* wet = wob + 262144;              // 65536 + 4096 pad (panel-16 DMA overread)

    cvt_all_kernel<<<5184, 256, 0, stream>>>(x, Wq, Wk, Wv, Wo, We,
                                             xbf, wqb, wkb, wvb, wob, wet);
    proj_mfma_kernel<<<dim3(4, 64, 3), 256, 0, stream>>>(xbf, wqb, wkb, wvb,
                                                         qw, kw, vtg,
                                                         0.125f * 1.44269504089f);
    attn_v9_kernel<<<1024, 256, 0, stream>>>(qw, kw, vtg, wet, awb);
    out_mfma_kernel<<<dim3(8, 128), 256, 0, stream>>>(awb, wob, bo, (float*)d_out);
}